// Round 8
// baseline (266.906 us; speedup 1.0000x reference)
//
#include <hip/hip_runtime.h>
#include <hip/hip_bf16.h>
#include <stdint.h>

#define B_   2
#define N_   2048
#define DIN  2048
#define DOUT 2048
#define H_   32
#define G_   8
#define HD_  64
#define M_   (B_*N_)   // 4096

using short8 = __attribute__((ext_vector_type(8))) short;
using f32x4  = __attribute__((ext_vector_type(4))) float;
using f32x16 = __attribute__((ext_vector_type(16))) float;
using int4v  = __attribute__((ext_vector_type(4))) int;

__device__ __forceinline__ unsigned short f2bf(float f) {
  unsigned int u = __float_as_uint(f);
  unsigned int r = u + 0x7FFFu + ((u >> 16) & 1u);
  return (unsigned short)(r >> 16);
}
__device__ __forceinline__ float bf2f(unsigned short h) {
  return __uint_as_float(((unsigned int)h) << 16);
}

// ---------------- elementwise f32 -> bf16 (4 elems/thread) ----------------
__global__ void k_cvt(const float* __restrict__ in, unsigned short* __restrict__ out, int n4) {
  int i = blockIdx.x * 256 + threadIdx.x;
  if (i >= n4) return;
  float4 v = reinterpret_cast<const float4*>(in)[i];
  uint2 o;
  o.x = (unsigned int)f2bf(v.x) | ((unsigned int)f2bf(v.y) << 16);
  o.y = (unsigned int)f2bf(v.z) | ((unsigned int)f2bf(v.w) << 16);
  reinterpret_cast<uint2*>(out)[i] = o;
}

// ---------------- transpose + convert: W (R x C) f32 -> Wt (C x R) bf16 ----------------
__global__ void k_transpose(const float* __restrict__ W, unsigned short* __restrict__ Wt,
                            int R, int C) {
  __shared__ float tile[32][33];
  int c0 = blockIdx.x * 32, r0 = blockIdx.y * 32;
  int tx = threadIdx.x, ty = threadIdx.y;  // (32,8)
  #pragma unroll
  for (int j = 0; j < 4; ++j)
    tile[ty + j*8][tx] = W[(size_t)(r0 + ty + j*8) * C + c0 + tx];
  __syncthreads();
  #pragma unroll
  for (int j = 0; j < 4; ++j)
    Wt[(size_t)(c0 + ty + j*8) * R + r0 + tx] = f2bf(tile[tx][ty + j*8]);
}

// ---------------- bf16 V-transpose: KVb V-half -> Vt[(b*8+g)*64 + d][n] ----------------
__global__ void k_vtrans(const unsigned short* __restrict__ KV, unsigned short* __restrict__ Vt) {
  __shared__ unsigned short tile[32][33];
  int nt = blockIdx.x;   // 0..63 (n tile)
  int dt = blockIdx.y;   // 0..1  (d tile)
  int bg = blockIdx.z;   // 0..15 (b*8+g)
  int b = bg >> 3, g = bg & 7;
  int tx = threadIdx.x, ty = threadIdx.y;  // (32,8)
  const unsigned short* src = KV + (size_t)(b*2048 + nt*32) * 1024 + 512 + g*64 + dt*32;
  #pragma unroll
  for (int j = 0; j < 4; ++j)
    tile[ty + j*8][tx] = src[(size_t)(ty + j*8) * 1024 + tx];   // [n_local][d_local]
  __syncthreads();
  unsigned short* dst = Vt + ((size_t)bg*64 + dt*32) * (size_t)N_ + nt*32;
  #pragma unroll
  for (int j = 0; j < 4; ++j)
    dst[(size_t)(ty + j*8) * N_ + tx] = tile[tx][ty + j*8];     // [d_local][n_local]
}

// ---------------- fragment-linear K/V tile pack ----------------
// Kp/Vp: per (bg, t) a 2048-element (4 KB) tile laid out EXACTLY in load order:
//   element index = chunk*512 + lane*8 + j.
__global__ void __launch_bounds__(64)
k_pack(const unsigned short* __restrict__ KV, const unsigned short* __restrict__ Vt,
       unsigned short* __restrict__ Kp, unsigned short* __restrict__ Vp) {
  const int t  = blockIdx.x;      // 0..63
  const int bg = blockIdx.y;      // 0..15
  const int b = bg >> 3, g = bg & 7;
  const int l = threadIdx.x;
  const int lo = l & 31, hi = l >> 5;
  const size_t base = ((size_t)bg*64 + t) * 2048;
  #pragma unroll
  for (int c = 0; c < 4; ++c) {
    short8 kv = *reinterpret_cast<const short8*>(
        KV + (size_t)(b*2048 + t*32 + lo) * 1024 + g*64 + c*16 + hi*8);
    *reinterpret_cast<short8*>(Kp + base + c*512 + l*8) = kv;
    short8 vv = *reinterpret_cast<const short8*>(
        Vt + ((size_t)bg*64 + (c>>1)*32 + lo) * (size_t)N_ + t*32 + (c&1)*16 + hi*8);
    *reinterpret_cast<short8*>(Vp + base + c*512 + l*8) = vv;
  }
}

// ---------------- in-place RoPE on bf16, optional output scale ----------------
__global__ void k_rope(unsigned short* __restrict__ X, const float* __restrict__ cosT,
                       const float* __restrict__ sinT, int nheads, int rowStride, float scale) {
  int idx = blockIdx.x * 256 + threadIdx.x;
  int dp  = idx & 31;
  int hh  = (idx >> 5) % nheads;
  int row = idx / (32 * nheads);
  if (row >= M_) return;
  int n = row & (N_ - 1);
  float c = cosT[n*HD_ + dp] * scale, s = sinT[n*HD_ + dp] * scale;
  unsigned short* p = X + (size_t)row * rowStride + hh*HD_ + dp;
  float x1 = bf2f(p[0]), x2 = bf2f(p[32]);
  p[0]  = f2bf(x1*c - x2*s);
  p[32] = f2bf(x2*c + x1*s);
}

// ---------------- bf16 GEMM, B given transposed (Bt: N x K row-major) ----------------
// T1: bijective XCD swizzle (m204) so each XCD's L2 serves a contiguous tile strip.
template <typename OUT>
__global__ void __launch_bounds__(256)
k_gemm_bt(const unsigned short* __restrict__ A, const unsigned short* __restrict__ Bt,
          OUT* __restrict__ C, int M, int N, int K) {
  __shared__ unsigned short As[128 * 32];
  __shared__ unsigned short Bs[128 * 32];
  const int tid  = threadIdx.x;
  const int wid  = tid >> 6, l = tid & 63;
  const int lrow = l & 15,  lk = l >> 4;
  const int wm = wid >> 1,  wn = wid & 1;

  // XCD-aware remap: hardware sends block n to XCD n%8; give each XCD a
  // contiguous range of tile ids.
  const int gx   = gridDim.x;
  const int nwg  = gx * gridDim.y;
  const int orig = blockIdx.y * gx + blockIdx.x;
  const int q8   = nwg >> 3, r8 = nwg & 7;
  const int xcd  = orig & 7, lin = orig >> 3;
  const int wg   = (xcd < r8 ? xcd*(q8+1) : r8*(q8+1) + (xcd - r8)*q8) + lin;
  const int bx   = wg % gx, by = wg / gx;

  const int rowA0 = by * 128, rowB0 = bx * 128;

  f32x4 acc[4][4];
  #pragma unroll
  for (int m = 0; m < 4; ++m)
    #pragma unroll
    for (int n = 0; n < 4; ++n)
      #pragma unroll
      for (int r = 0; r < 4; ++r) acc[m][n][r] = 0.f;

  int srow[2], scol[2];
  #pragma unroll
  for (int issue = 0; issue < 2; ++issue) {
    int slot = issue*4096 + wid*1024 + l*16;
    int row  = slot >> 6;
    int cp   = (slot >> 4) & 3;
    int sw   = (row & 3) ^ ((row >> 2) & 3);
    srow[issue] = row;
    scol[issue] = (cp ^ sw) * 8;
  }
  const int swr    = (lrow & 3) ^ ((lrow >> 2) & 3);
  const int rchunk = (lk ^ swr) * 8;

  for (int kt = 0; kt < K; kt += 32) {
    __syncthreads();
    #pragma unroll
    for (int issue = 0; issue < 2; ++issue) {
      const unsigned short* ga = A  + (size_t)(rowA0 + srow[issue]) * K + kt + scol[issue];
      const unsigned short* gb = Bt + (size_t)(rowB0 + srow[issue]) * K + kt + scol[issue];
      __builtin_amdgcn_global_load_lds(
          (const __attribute__((address_space(1))) unsigned int*)ga,
          (__attribute__((address_space(3))) unsigned int*)((char*)As + issue*4096 + wid*1024),
          16, 0, 0);
      __builtin_amdgcn_global_load_lds(
          (const __attribute__((address_space(1))) unsigned int*)gb,
          (__attribute__((address_space(3))) unsigned int*)((char*)Bs + issue*4096 + wid*1024),
          16, 0, 0);
    }
    asm volatile("s_waitcnt vmcnt(0)" ::: "memory");
    __syncthreads();

    short8 av[4], bv[4];
    #pragma unroll
    for (int m = 0; m < 4; ++m)
      av[m] = *reinterpret_cast<const short8*>(&As[(wm*64 + m*16 + lrow)*32 + rchunk]);
    #pragma unroll
    for (int n = 0; n < 4; ++n)
      bv[n] = *reinterpret_cast<const short8*>(&Bs[(wn*64 + n*16 + lrow)*32 + rchunk]);
    #pragma unroll
    for (int m = 0; m < 4; ++m)
      #pragma unroll
      for (int n = 0; n < 4; ++n)
        acc[m][n] = __builtin_amdgcn_mfma_f32_16x16x32_bf16(av[m], bv[n], acc[m][n], 0, 0, 0);
  }

  #pragma unroll
  for (int m = 0; m < 4; ++m) {
    int row0 = rowA0 + wm*64 + m*16 + lk*4;
    #pragma unroll
    for (int n = 0; n < 4; ++n) {
      int col = rowB0 + wn*64 + n*16 + lrow;
      #pragma unroll
      for (int r = 0; r < 4; ++r) {
        float v = acc[m][n][r];
        if constexpr (sizeof(OUT) == 2) C[(size_t)(row0 + r) * N + col] = (OUT)f2bf(v);
        else                            C[(size_t)(row0 + r) * N + col] = v;
      }
    }
  }
}

// ---------------- causal GQA flash attention v8 ----------------
// 4-wave blocks (4 heads of same (b,g,qt)) with K/V staged in SHARED LDS via
// global_load_lds (fragment-linear layout preserved), double-buffered, one
// __syncthreads per tile (T3-minimum 2-phase + T14 issue-early). Cuts ~64
// K/V regs per wave -> higher occupancy; 4 waves share one K/V fetch.
// T5 setprio around MFMA clusters; T13 defer-max; T12 permlane P-pack.
__global__ void __launch_bounds__(256, 3)
k_attn(const unsigned short* __restrict__ Q, const unsigned short* __restrict__ Kp,
       const unsigned short* __restrict__ Vp, unsigned short* __restrict__ ctx) {
  __shared__ unsigned short kvlds[2][4096];   // [buf][ K:0..2047 | V:2048..4095 ]
  const int bid = blockIdx.x;            // 0..1023
  const int c   = bid & 15;              // (b,g) chunk -> fixed XCD
  const int b   = c >> 3, g = c & 7;
  const int qt  = 63 - (bid >> 4);       // longest first
  const int tid = threadIdx.x;
  const int hh  = tid >> 6;              // wave id = head within group
  const int h   = g*4 + hh;
  const int l   = tid & 63;
  const int lq  = l & 31, hi = l >> 5;

  const unsigned short* qp = Q + (size_t)(b*N_ + qt*32 + lq) * DOUT + h*HD_ + hi*8;
  short8 qf0 = *reinterpret_cast<const short8*>(qp);
  short8 qf1 = *reinterpret_cast<const short8*>(qp + 16);
  short8 qf2 = *reinterpret_cast<const short8*>(qp + 32);
  short8 qf3 = *reinterpret_cast<const short8*>(qp + 48);

  // staging source: wave hh stages quarter hh of each 4 KB tile (lane gives 16B)
  const unsigned short* ksrc = Kp + (size_t)c*64*2048 + hh*512 + l*8;
  const unsigned short* vsrc = Vp + (size_t)c*64*2048 + hh*512 + l*8;

  f32x16 acc0, acc1;
  #pragma unroll
  for (int r = 0; r < 16; ++r) { acc0[r] = 0.f; acc1[r] = 0.f; }
  float m_run = -3.0e38f, l_run = 0.f;

  auto stage = [&](int t, int buf) {
    __builtin_amdgcn_global_load_lds(
        (const __attribute__((address_space(1))) unsigned int*)(ksrc + (size_t)t*2048),
        (__attribute__((address_space(3))) unsigned int*)((char*)&kvlds[buf][0] + hh*1024),
        16, 0, 0);
    __builtin_amdgcn_global_load_lds(
        (const __attribute__((address_space(1))) unsigned int*)(vsrc + (size_t)t*2048),
        (__attribute__((address_space(3))) unsigned int*)((char*)&kvlds[buf][2048] + hh*1024),
        16, 0, 0);
  };

  auto body = [&](bool diag, int buf) {
    short8 ka = *reinterpret_cast<const short8*>(&kvlds[buf][l*8]);
    short8 kb = *reinterpret_cast<const short8*>(&kvlds[buf][512 + l*8]);
    short8 kc = *reinterpret_cast<const short8*>(&kvlds[buf][1024 + l*8]);
    short8 kd = *reinterpret_cast<const short8*>(&kvlds[buf][1536 + l*8]);

    f32x16 s;
    #pragma unroll
    for (int r = 0; r < 16; ++r) s[r] = 0.f;
    __builtin_amdgcn_s_setprio(1);
    s = __builtin_amdgcn_mfma_f32_32x32x16_bf16(ka, qf0, s, 0, 0, 0);
    s = __builtin_amdgcn_mfma_f32_32x32x16_bf16(kb, qf1, s, 0, 0, 0);
    s = __builtin_amdgcn_mfma_f32_32x32x16_bf16(kc, qf2, s, 0, 0, 0);
    s = __builtin_amdgcn_mfma_f32_32x32x16_bf16(kd, qf3, s, 0, 0, 0);
    __builtin_amdgcn_s_setprio(0);

    if (diag) {
      #pragma unroll
      for (int r = 0; r < 16; ++r) {
        const int ko = (r & 3) + 8*(r >> 2) + 4*hi;
        s[r] = (ko <= lq) ? s[r] : -3.0e38f;
      }
    }
    float t0 = fmaxf(fmaxf(s[0], s[1]), s[2]);
    float t1 = fmaxf(fmaxf(s[3], s[4]), s[5]);
    float t2 = fmaxf(fmaxf(s[6], s[7]), s[8]);
    float t3 = fmaxf(fmaxf(s[9], s[10]), s[11]);
    float t4 = fmaxf(fmaxf(s[12], s[13]), s[14]);
    float mt = fmaxf(fmaxf(fmaxf(t0, t1), fmaxf(t2, t3)), fmaxf(t4, s[15]));
    mt = fmaxf(mt, __shfl_xor(mt, 32));
    if (!__all(mt <= m_run + 8.f)) {          // T13 defer-max
      float nm = fmaxf(m_run, mt);
      float fr = exp2f(m_run - nm);
      m_run = nm;
      l_run *= fr;
      #pragma unroll
      for (int r = 0; r < 16; ++r) { acc0[r] *= fr; acc1[r] *= fr; }
    }
    unsigned int w[8];
    float ps = 0.f;
    #pragma unroll
    for (int i = 0; i < 8; ++i) {
      float p0 = exp2f(s[2*i]   - m_run);
      float p1 = exp2f(s[2*i+1] - m_run);
      ps += p0 + p1;
      asm("v_cvt_pk_bf16_f32 %0, %1, %2" : "=v"(w[i]) : "v"(p0), "v"(p1));
    }
    ps += __shfl_xor(ps, 32);
    l_run += ps;

    // T12: permlane32_swap builds both halves of each P fragment word
    unsigned int x0 = w[0], x1 = w[1], y0 = w[2], y1 = w[3];
    asm("v_permlane32_swap_b32 %0, %1" : "+v"(x0), "+v"(y0));
    asm("v_permlane32_swap_b32 %0, %1" : "+v"(x1), "+v"(y1));
    unsigned int x2 = w[4], x3 = w[5], y2 = w[6], y3 = w[7];
    asm("v_permlane32_swap_b32 %0, %1" : "+v"(x2), "+v"(y2));
    asm("v_permlane32_swap_b32 %0, %1" : "+v"(x3), "+v"(y3));
    int4v p0i, p1i;
    p0i[0] = (int)x0; p0i[1] = (int)x1; p0i[2] = (int)y0; p0i[3] = (int)y1;
    p1i[0] = (int)x2; p1i[1] = (int)x3; p1i[2] = (int)y2; p1i[3] = (int)y3;
    short8 pa0 = __builtin_bit_cast(short8, p0i);
    short8 pa1 = __builtin_bit_cast(short8, p1i);

    short8 va = *reinterpret_cast<const short8*>(&kvlds[buf][2048 + l*8]);
    short8 vb = *reinterpret_cast<const short8*>(&kvlds[buf][2560 + l*8]);
    short8 vc = *reinterpret_cast<const short8*>(&kvlds[buf][3072 + l*8]);
    short8 vd = *reinterpret_cast<const short8*>(&kvlds[buf][3584 + l*8]);

    __builtin_amdgcn_s_setprio(1);
    acc0 = __builtin_amdgcn_mfma_f32_32x32x16_bf16(va, pa0, acc0, 0, 0, 0);
    acc0 = __builtin_amdgcn_mfma_f32_32x32x16_bf16(vb, pa1, acc0, 0, 0, 0);
    acc1 = __builtin_amdgcn_mfma_f32_32x32x16_bf16(vc, pa0, acc1, 0, 0, 0);
    acc1 = __builtin_amdgcn_mfma_f32_32x32x16_bf16(vd, pa1, acc1, 0, 0, 0);
    __builtin_amdgcn_s_setprio(0);
  };

  stage(0, 0);
  __syncthreads();
  for (int t = 0; ; ) {
    const int cur = t & 1;
    if (t < qt) stage(t + 1, cur ^ 1);   // issue-early: HBM/L2 latency hides under compute
    body(t == qt, cur);
    if (++t > qt) break;
    __syncthreads();                     // drains vmcnt (stage done) + lgkm (reads done)
  }

  const float rl = 1.f / l_run;
  unsigned short* op = ctx + (size_t)(b*N_ + qt*32 + lq) * DOUT + h*HD_ + 4*hi;
  #pragma unroll
  for (int dt = 0; dt < 2; ++dt) {
    #pragma unroll
    for (int rq = 0; rq < 4; ++rq) {
      const float a0 = (dt ? acc1[4*rq+0] : acc0[4*rq+0]) * rl;
      const float a1 = (dt ? acc1[4*rq+1] : acc0[4*rq+1]) * rl;
      const float a2 = (dt ? acc1[4*rq+2] : acc0[4*rq+2]) * rl;
      const float a3 = (dt ? acc1[4*rq+3] : acc0[4*rq+3]) * rl;
      ushort4 st;
      st.x = f2bf(a0); st.y = f2bf(a1); st.z = f2bf(a2); st.w = f2bf(a3);
      *reinterpret_cast<ushort4*>(op + dt*32 + rq*8) = st;
    }
  }
}

// ---------------- launcher ----------------
extern "C" void kernel_launch(void* const* d_in, const int* in_sizes, int n_in,
                              void* d_out, int out_size, void* d_ws, size_t ws_size,
                              hipStream_t stream) {
  const float* x    = (const float*)d_in[0];
  const float* cosT = (const float*)d_in[1];
  const float* sinT = (const float*)d_in[2];
  const float* Wq   = (const float*)d_in[4];
  const float* Wk   = (const float*)d_in[5];
  const float* Wv   = (const float*)d_in[6];
  const float* Wo   = (const float*)d_in[7];
  float* out = (float*)d_out;

  char* ws = (char*)d_ws;
  unsigned short* xb    = (unsigned short*)(ws);               // 16 MB (reused as ctxb)
  unsigned short* ctxb  = xb;
  unsigned short* Wq_t  = (unsigned short*)(ws + 16777216);    // 8 MB; first 4 MB reused as Vt
  unsigned short* Vt    = Wq_t;
  unsigned short* Kp    = (unsigned short*)(ws + 20971520);    // 4 MB (2nd half of Wq_t region)
  unsigned short* Wkv_t = (unsigned short*)(ws + 25165824);    // 4 MB (reused as Vp)
  unsigned short* Vp    = Wkv_t;
  unsigned short* Wo_t  = (unsigned short*)(ws + 29360128);    // 8 MB
  unsigned short* Qb    = (unsigned short*)(ws + 37748736);    // 16 MB
  unsigned short* KVb   = (unsigned short*)(ws + 54525952);    // 8 MB

  k_cvt<<<dim3(M_*DIN/4/256), dim3(256), 0, stream>>>(x, xb, M_*DIN/4);

  dim3 tb(32, 8);
  k_transpose<<<dim3(DOUT/32, DIN/32), tb, 0, stream>>>(Wq, Wq_t, DIN, DOUT);
  k_transpose<<<dim3(512/32,  DIN/32), tb, 0, stream>>>(Wk, Wkv_t, DIN, 512);
  k_transpose<<<dim3(512/32,  DIN/32), tb, 0, stream>>>(Wv, Wkv_t + (size_t)512*DIN, DIN, 512);
  k_transpose<<<dim3(DOUT/32, DOUT/32), tb, 0, stream>>>(Wo, Wo_t, DOUT, DOUT);

  k_gemm_bt<unsigned short><<<dim3(DOUT/128, M_/128), 256, 0, stream>>>(xb, Wq_t,  Qb,  M_, DOUT, DIN);
  k_gemm_bt<unsigned short><<<dim3(1024/128, M_/128), 256, 0, stream>>>(xb, Wkv_t, KVb, M_, 1024, DIN);

  const float QSCALE = 0.125f * 1.44269504088896f;   // 1/sqrt(64) * log2(e)
  k_rope<<<dim3(M_*H_*32/256), dim3(256), 0, stream>>>(Qb,  cosT, sinT, H_, DOUT, QSCALE);
  k_rope<<<dim3(M_*G_*32/256), dim3(256), 0, stream>>>(KVb, cosT, sinT, G_, 1024, 1.0f);

  k_vtrans<<<dim3(64, 2, 16), tb, 0, stream>>>(KVb, Vt);
  k_pack<<<dim3(64, 16), dim3(64), 0, stream>>>(KVb, Vt, Kp, Vp);

  k_attn<<<dim3(1024), dim3(256), 0, stream>>>(Qb, Kp, Vp, ctxb);

  k_gemm_bt<float><<<dim3(DOUT/128, M_/128), 256, 0, stream>>>(ctxb, Wo_t, out, M_, DOUT, DIN);
}

// Round 9
// 242.355 us; speedup vs baseline: 1.1013x; 1.1013x over previous
//
#include <hip/hip_runtime.h>
#include <hip/hip_bf16.h>
#include <stdint.h>

#define B_   2
#define N_   2048
#define DIN  2048
#define DOUT 2048
#define H_   32
#define G_   8
#define HD_  64
#define M_   (B_*N_)   // 4096
#define QKS  2560      // QKV buffer row stride (Q 0..2047 | K 2048..2559; V diverted)

using short8 = __attribute__((ext_vector_type(8))) short;
using f32x4  = __attribute__((ext_vector_type(4))) float;
using f32x16 = __attribute__((ext_vector_type(16))) float;
using int4v  = __attribute__((ext_vector_type(4))) int;

__device__ __forceinline__ unsigned short f2bf(float f) {
  unsigned int u = __float_as_uint(f);
  unsigned int r = u + 0x7FFFu + ((u >> 16) & 1u);
  return (unsigned short)(r >> 16);
}
__device__ __forceinline__ float bf2f(unsigned short h) {
  return __uint_as_float(((unsigned int)h) << 16);
}

// ---------------- elementwise f32 -> bf16 (4 elems/thread) ----------------
__global__ void k_cvt(const float* __restrict__ in, unsigned short* __restrict__ out, int n4) {
  int i = blockIdx.x * 256 + threadIdx.x;
  if (i >= n4) return;
  float4 v = reinterpret_cast<const float4*>(in)[i];
  uint2 o;
  o.x = (unsigned int)f2bf(v.x) | ((unsigned int)f2bf(v.y) << 16);
  o.y = (unsigned int)f2bf(v.z) | ((unsigned int)f2bf(v.w) << 16);
  reinterpret_cast<uint2*>(out)[i] = o;
}

// ---------------- transpose + convert: W (R x C) f32 -> Wt (C x R) bf16 ----------------
__global__ void k_transpose(const float* __restrict__ W, unsigned short* __restrict__ Wt,
                            int R, int C) {
  __shared__ float tile[32][33];
  int c0 = blockIdx.x * 32, r0 = blockIdx.y * 32;
  int tx = threadIdx.x, ty = threadIdx.y;  // (32,8)
  #pragma unroll
  for (int j = 0; j < 4; ++j)
    tile[ty + j*8][tx] = W[(size_t)(r0 + ty + j*8) * C + c0 + tx];
  __syncthreads();
  #pragma unroll
  for (int j = 0; j < 4; ++j)
    Wt[(size_t)(c0 + ty + j*8) * R + r0 + tx] = f2bf(tile[tx][ty + j*8]);
}

// ---------------- fragment-linear K tile pack (from QKV buffer) ----------------
// Kp: per (bg, t) a 2048-elem (4KB) tile in exact load order: idx = c*512 + l*8 + j.
__global__ void __launch_bounds__(64)
k_pack(const unsigned short* __restrict__ QKV, unsigned short* __restrict__ Kp) {
  const int t  = blockIdx.x;      // 0..63
  const int bg = blockIdx.y;      // 0..15
  const int b = bg >> 3, g = bg & 7;
  const int l = threadIdx.x;
  const int lo = l & 31, hi = l >> 5;
  const size_t base = ((size_t)bg*64 + t) * 2048;
  #pragma unroll
  for (int c = 0; c < 4; ++c) {
    short8 kv = *reinterpret_cast<const short8*>(
        QKV + (size_t)(b*2048 + t*32 + lo) * QKS + 2048 + g*64 + c*16 + hi*8);
    *reinterpret_cast<short8*>(Kp + base + c*512 + l*8) = kv;
  }
}

// ---------------- in-place RoPE on bf16, optional output scale ----------------
__global__ void k_rope(unsigned short* __restrict__ X, const float* __restrict__ cosT,
                       const float* __restrict__ sinT, int nheads, int rowStride, float scale) {
  int idx = blockIdx.x * 256 + threadIdx.x;
  int dp  = idx & 31;
  int hh  = (idx >> 5) % nheads;
  int row = idx / (32 * nheads);
  if (row >= M_) return;
  int n = row & (N_ - 1);
  float c = cosT[n*HD_ + dp] * scale, s = sinT[n*HD_ + dp] * scale;
  unsigned short* p = X + (size_t)row * rowStride + hh*HD_ + dp;
  float x1 = bf2f(p[0]), x2 = bf2f(p[32]);
  p[0]  = f2bf(x1*c - x2*s);
  p[32] = f2bf(x2*c + x1*s);
}

// ---------------- bf16 GEMM, B transposed; optional V-diversion epilogue ----------------
// T1 bijective XCD swizzle. If VOUT and col-tile >= 2560, the output is V:
// written directly to Vp in fragment-linear attention layout (no C write).
template <typename OUT, bool VOUT>
__global__ void __launch_bounds__(256)
k_gemm_bt(const unsigned short* __restrict__ A, const unsigned short* __restrict__ Bt,
          OUT* __restrict__ C, unsigned short* __restrict__ Vp,
          int M, int N, int ldc, int K) {
  __shared__ unsigned short As[128 * 32];
  __shared__ unsigned short Bs[128 * 32];
  const int tid  = threadIdx.x;
  const int wid  = tid >> 6, l = tid & 63;
  const int lrow = l & 15,  lk = l >> 4;
  const int wm = wid >> 1,  wn = wid & 1;

  const int gx   = gridDim.x;
  const int nwg  = gx * gridDim.y;
  const int orig = blockIdx.y * gx + blockIdx.x;
  const int q8   = nwg >> 3, r8 = nwg & 7;
  const int xcd  = orig & 7, lin = orig >> 3;
  const int wg   = (xcd < r8 ? xcd*(q8+1) : r8*(q8+1) + (xcd - r8)*q8) + lin;
  const int bx   = wg % gx, by = wg / gx;

  const int rowA0 = by * 128, rowB0 = bx * 128;

  f32x4 acc[4][4];
  #pragma unroll
  for (int m = 0; m < 4; ++m)
    #pragma unroll
    for (int n = 0; n < 4; ++n)
      #pragma unroll
      for (int r = 0; r < 4; ++r) acc[m][n][r] = 0.f;

  int srow[2], scol[2];
  #pragma unroll
  for (int issue = 0; issue < 2; ++issue) {
    int slot = issue*4096 + wid*1024 + l*16;
    int row  = slot >> 6;
    int cp   = (slot >> 4) & 3;
    int sw   = (row & 3) ^ ((row >> 2) & 3);
    srow[issue] = row;
    scol[issue] = (cp ^ sw) * 8;
  }
  const int swr    = (lrow & 3) ^ ((lrow >> 2) & 3);
  const int rchunk = (lk ^ swr) * 8;

  for (int kt = 0; kt < K; kt += 32) {
    __syncthreads();
    #pragma unroll
    for (int issue = 0; issue < 2; ++issue) {
      const unsigned short* ga = A  + (size_t)(rowA0 + srow[issue]) * K + kt + scol[issue];
      const unsigned short* gb = Bt + (size_t)(rowB0 + srow[issue]) * K + kt + scol[issue];
      __builtin_amdgcn_global_load_lds(
          (const __attribute__((address_space(1))) unsigned int*)ga,
          (__attribute__((address_space(3))) unsigned int*)((char*)As + issue*4096 + wid*1024),
          16, 0, 0);
      __builtin_amdgcn_global_load_lds(
          (const __attribute__((address_space(1))) unsigned int*)gb,
          (__attribute__((address_space(3))) unsigned int*)((char*)Bs + issue*4096 + wid*1024),
          16, 0, 0);
    }
    asm volatile("s_waitcnt vmcnt(0)" ::: "memory");
    __syncthreads();

    short8 av[4], bv[4];
    #pragma unroll
    for (int m = 0; m < 4; ++m)
      av[m] = *reinterpret_cast<const short8*>(&As[(wm*64 + m*16 + lrow)*32 + rchunk]);
    #pragma unroll
    for (int n = 0; n < 4; ++n)
      bv[n] = *reinterpret_cast<const short8*>(&Bs[(wn*64 + n*16 + lrow)*32 + rchunk]);
    #pragma unroll
    for (int m = 0; m < 4; ++m)
      #pragma unroll
      for (int n = 0; n < 4; ++n)
        acc[m][n] = __builtin_amdgcn_mfma_f32_16x16x32_bf16(av[m], bv[n], acc[m][n], 0, 0, 0);
  }

  if constexpr (VOUT) {
    if (rowB0 >= 2560) {          // V block: direct fragment-linear Vp write
      const int bq = rowA0 >> 11;
      #pragma unroll
      for (int m = 0; m < 4; ++m) {
        const int row0 = rowA0 + wm*64 + m*16 + lk*4;
        const int key  = row0 & 2047;
        const size_t tbase = (size_t)(key >> 5)*2048 + (size_t)((key >> 4) & 1)*512
                           + (size_t)((key >> 3) & 1)*256 + (size_t)(key & 7);
        #pragma unroll
        for (int n = 0; n < 4; ++n) {
          const int cv = rowB0 + wn*64 + n*16 + lrow - 2560;
          const int gq = cv >> 6, d = cv & 63;
          const size_t addr = (size_t)(bq*8 + gq)*131072 + tbase
                            + (size_t)(d >> 5)*1024 + (size_t)(d & 31)*8;
          ushort4 st;
          st.x = f2bf(acc[m][n][0]); st.y = f2bf(acc[m][n][1]);
          st.z = f2bf(acc[m][n][2]); st.w = f2bf(acc[m][n][3]);
          *reinterpret_cast<ushort4*>(Vp + addr) = st;
        }
      }
      return;
    }
  }

  #pragma unroll
  for (int m = 0; m < 4; ++m) {
    int row0 = rowA0 + wm*64 + m*16 + lk*4;
    #pragma unroll
    for (int n = 0; n < 4; ++n) {
      int col = rowB0 + wn*64 + n*16 + lrow;
      #pragma unroll
      for (int r = 0; r < 4; ++r) {
        float v = acc[m][n][r];
        if constexpr (sizeof(OUT) == 2) C[(size_t)(row0 + r) * ldc + col] = (OUT)f2bf(v);
        else                            C[(size_t)(row0 + r) * ldc + col] = v;
      }
    }
  }
}

// ---------------- causal GQA flash attention v9: KVBLK=64 ----------------
// 4-wave blocks (4 heads of one (b,g,qt)); K/V staged in LDS pairs of tiles (16KB)
// via global_load_lds, double-buffered; ONE softmax round per 64 keys (halves
// shfl/loop/barrier/defer overhead vs v8). T5 setprio; T13 defer-max; T12 permlane.
__global__ void __launch_bounds__(256, 3)
k_attn(const unsigned short* __restrict__ Q, const unsigned short* __restrict__ Kp,
       const unsigned short* __restrict__ Vp, unsigned short* __restrict__ ctx) {
  __shared__ unsigned short kv[2][8192];   // [buf][ K pair 0..4095 | V pair 4096..8191 ]
  const int bid = blockIdx.x;            // 0..1023
  const int c   = bid & 15;              // (b,g) chunk -> fixed XCD
  const int b   = c >> 3, g = c & 7;
  const int qt  = 63 - (bid >> 4);       // longest first
  const int tid = threadIdx.x;
  const int hh  = tid >> 6;              // wave id = head within group
  const int h   = g*4 + hh;
  const int l   = tid & 63;
  const int lq  = l & 31, hi = l >> 5;

  const unsigned short* qp = Q + (size_t)(b*N_ + qt*32 + lq) * QKS + h*HD_ + hi*8;
  short8 qf0 = *reinterpret_cast<const short8*>(qp);
  short8 qf1 = *reinterpret_cast<const short8*>(qp + 16);
  short8 qf2 = *reinterpret_cast<const short8*>(qp + 32);
  short8 qf3 = *reinterpret_cast<const short8*>(qp + 48);

  const unsigned short* ksrc = Kp + (size_t)c*131072 + hh*512 + l*8;
  const unsigned short* vsrc = Vp + (size_t)c*131072 + hh*512 + l*8;

  f32x16 acc0, acc1;
  #pragma unroll
  for (int r = 0; r < 16; ++r) { acc0[r] = 0.f; acc1[r] = 0.f; }
  float m_run = -3.0e38f, l_run = 0.f;

  auto stage = [&](int p, int buf) {
    #pragma unroll
    for (int i = 0; i < 2; ++i) {
      __builtin_amdgcn_global_load_lds(
          (const __attribute__((address_space(1))) unsigned int*)(ksrc + (size_t)p*4096 + i*2048),
          (__attribute__((address_space(3))) unsigned int*)((char*)&kv[buf][i*2048] + hh*1024),
          16, 0, 0);
      __builtin_amdgcn_global_load_lds(
          (const __attribute__((address_space(1))) unsigned int*)(vsrc + (size_t)p*4096 + i*2048),
          (__attribute__((address_space(3))) unsigned int*)((char*)&kv[buf][4096 + i*2048] + hh*1024),
          16, 0, 0);
    }
  };

  auto body = [&](int p, int buf) {
    f32x16 s0, s1;
    #pragma unroll
    for (int r = 0; r < 16; ++r) { s0[r] = 0.f; s1[r] = 0.f; }
    {
      short8 ka = *reinterpret_cast<const short8*>(&kv[buf][l*8]);
      short8 kb = *reinterpret_cast<const short8*>(&kv[buf][512 + l*8]);
      short8 kc = *reinterpret_cast<const short8*>(&kv[buf][1024 + l*8]);
      short8 kd = *reinterpret_cast<const short8*>(&kv[buf][1536 + l*8]);
      short8 ke = *reinterpret_cast<const short8*>(&kv[buf][2048 + l*8]);
      short8 kf = *reinterpret_cast<const short8*>(&kv[buf][2560 + l*8]);
      short8 kg = *reinterpret_cast<const short8*>(&kv[buf][3072 + l*8]);
      short8 kh = *reinterpret_cast<const short8*>(&kv[buf][3584 + l*8]);
      __builtin_amdgcn_s_setprio(1);
      s0 = __builtin_amdgcn_mfma_f32_32x32x16_bf16(ka, qf0, s0, 0, 0, 0);
      s1 = __builtin_amdgcn_mfma_f32_32x32x16_bf16(ke, qf0, s1, 0, 0, 0);
      s0 = __builtin_amdgcn_mfma_f32_32x32x16_bf16(kb, qf1, s0, 0, 0, 0);
      s1 = __builtin_amdgcn_mfma_f32_32x32x16_bf16(kf, qf1, s1, 0, 0, 0);
      s0 = __builtin_amdgcn_mfma_f32_32x32x16_bf16(kc, qf2, s0, 0, 0, 0);
      s1 = __builtin_amdgcn_mfma_f32_32x32x16_bf16(kg, qf2, s1, 0, 0, 0);
      s0 = __builtin_amdgcn_mfma_f32_32x32x16_bf16(kd, qf3, s0, 0, 0, 0);
      s1 = __builtin_amdgcn_mfma_f32_32x32x16_bf16(kh, qf3, s1, 0, 0, 0);
      __builtin_amdgcn_s_setprio(0);
    }

    const bool d0 = (2*p == qt);
    const bool d1 = (2*p + 1 == qt);
    const bool f1 = (2*p + 1 > qt);
    float u0[16], u1[16];
    #pragma unroll
    for (int r = 0; r < 16; ++r) {
      const int ko = (r & 3) + 8*(r >> 2) + 4*hi;
      u0[r] = (!d0 || ko <= lq) ? s0[r] : -3.0e38f;
      u1[r] = f1 ? -3.0e38f : ((!d1 || ko <= lq) ? s1[r] : -3.0e38f);
    }
    float a8[8];
    #pragma unroll
    for (int i = 0; i < 8; ++i)
      a8[i] = fmaxf(fmaxf(u0[2*i], u0[2*i+1]), fmaxf(u1[2*i], u1[2*i+1]));
    float mt = fmaxf(fmaxf(fmaxf(a8[0], a8[1]), fmaxf(a8[2], a8[3])),
                     fmaxf(fmaxf(a8[4], a8[5]), fmaxf(a8[6], a8[7])));
    mt = fmaxf(mt, __shfl_xor(mt, 32));
    if (!__all(mt <= m_run + 8.f)) {          // T13 defer-max
      float nm = fmaxf(m_run, mt);
      float fr = exp2f(m_run - nm);
      m_run = nm;
      l_run *= fr;
      #pragma unroll
      for (int r = 0; r < 16; ++r) { acc0[r] *= fr; acc1[r] *= fr; }
    }
    unsigned int w0[8], w1[8];
    float ps = 0.f;
    #pragma unroll
    for (int i = 0; i < 8; ++i) {
      float e0 = exp2f(u0[2*i]   - m_run);
      float e1 = exp2f(u0[2*i+1] - m_run);
      float e2 = exp2f(u1[2*i]   - m_run);
      float e3 = exp2f(u1[2*i+1] - m_run);
      ps += (e0 + e1) + (e2 + e3);
      asm("v_cvt_pk_bf16_f32 %0, %1, %2" : "=v"(w0[i]) : "v"(e0), "v"(e1));
      asm("v_cvt_pk_bf16_f32 %0, %1, %2" : "=v"(w1[i]) : "v"(e2), "v"(e3));
    }
    ps += __shfl_xor(ps, 32);
    l_run += ps;

    // T12 permlane P-pack, per tile
    unsigned int x0 = w0[0], x1 = w0[1], y0 = w0[2], y1 = w0[3];
    asm("v_permlane32_swap_b32 %0, %1" : "+v"(x0), "+v"(y0));
    asm("v_permlane32_swap_b32 %0, %1" : "+v"(x1), "+v"(y1));
    unsigned int x2 = w0[4], x3 = w0[5], y2 = w0[6], y3 = w0[7];
    asm("v_permlane32_swap_b32 %0, %1" : "+v"(x2), "+v"(y2));
    asm("v_permlane32_swap_b32 %0, %1" : "+v"(x3), "+v"(y3));
    int4v p0i, p1i;
    p0i[0] = (int)x0; p0i[1] = (int)x1; p0i[2] = (int)y0; p0i[3] = (int)y1;
    p1i[0] = (int)x2; p1i[1] = (int)x3; p1i[2] = (int)y2; p1i[3] = (int)y3;
    short8 pa0 = __builtin_bit_cast(short8, p0i);
    short8 pa1 = __builtin_bit_cast(short8, p1i);

    unsigned int z0 = w1[0], z1 = w1[1], t0 = w1[2], t1 = w1[3];
    asm("v_permlane32_swap_b32 %0, %1" : "+v"(z0), "+v"(t0));
    asm("v_permlane32_swap_b32 %0, %1" : "+v"(z1), "+v"(t1));
    unsigned int z2 = w1[4], z3 = w1[5], t2 = w1[6], t3 = w1[7];
    asm("v_permlane32_swap_b32 %0, %1" : "+v"(z2), "+v"(t2));
    asm("v_permlane32_swap_b32 %0, %1" : "+v"(z3), "+v"(t3));
    int4v q0i, q1i;
    q0i[0] = (int)z0; q0i[1] = (int)z1; q0i[2] = (int)t0; q0i[3] = (int)t1;
    q1i[0] = (int)z2; q1i[1] = (int)z3; q1i[2] = (int)t2; q1i[3] = (int)t3;
    short8 pb0 = __builtin_bit_cast(short8, q0i);
    short8 pb1 = __builtin_bit_cast(short8, q1i);

    short8 v00 = *reinterpret_cast<const short8*>(&kv[buf][4096 + l*8]);
    short8 v01 = *reinterpret_cast<const short8*>(&kv[buf][4608 + l*8]);
    short8 v02 = *reinterpret_cast<const short8*>(&kv[buf][5120 + l*8]);
    short8 v03 = *reinterpret_cast<const short8*>(&kv[buf][5632 + l*8]);
    short8 v10 = *reinterpret_cast<const short8*>(&kv[buf][6144 + l*8]);
    short8 v11 = *reinterpret_cast<const short8*>(&kv[buf][6656 + l*8]);
    short8 v12 = *reinterpret_cast<const short8*>(&kv[buf][7168 + l*8]);
    short8 v13 = *reinterpret_cast<const short8*>(&kv[buf][7680 + l*8]);

    __builtin_amdgcn_s_setprio(1);
    acc0 = __builtin_amdgcn_mfma_f32_32x32x16_bf16(v00, pa0, acc0, 0, 0, 0);
    acc1 = __builtin_amdgcn_mfma_f32_32x32x16_bf16(v02, pa0, acc1, 0, 0, 0);
    acc0 = __builtin_amdgcn_mfma_f32_32x32x16_bf16(v01, pa1, acc0, 0, 0, 0);
    acc1 = __builtin_amdgcn_mfma_f32_32x32x16_bf16(v03, pa1, acc1, 0, 0, 0);
    acc0 = __builtin_amdgcn_mfma_f32_32x32x16_bf16(v10, pb0, acc0, 0, 0, 0);
    acc1 = __builtin_amdgcn_mfma_f32_32x32x16_bf16(v12, pb0, acc1, 0, 0, 0);
    acc0 = __builtin_amdgcn_mfma_f32_32x32x16_bf16(v11, pb1, acc0, 0, 0, 0);
    acc1 = __builtin_amdgcn_mfma_f32_32x32x16_bf16(v13, pb1, acc1, 0, 0, 0);
    __builtin_amdgcn_s_setprio(0);
  };

  const int npairs = (qt >> 1) + 1;
  stage(0, 0);
  __syncthreads();
  for (int p = 0; ; ) {
    const int cur = p & 1;
    if (p + 1 < npairs) stage(p + 1, cur ^ 1);
    body(p, cur);
    if (++p >= npairs) break;
    __syncthreads();
  }

  const float rl = 1.f / l_run;
  unsigned short* op = ctx + (size_t)(b*N_ + qt*32 + lq) * DOUT + h*HD_ + 4*hi;
  #pragma unroll
  for (int dt = 0; dt < 2; ++dt) {
    #pragma unroll
    for (int rq = 0; rq < 4; ++rq) {
      const float a0 = (dt ? acc1[4*rq+0] : acc0[4*rq+0]) * rl;
      const float a1 = (dt ? acc1[4*rq+1] : acc0[4*rq+1]) * rl;
      const float a2 = (dt ? acc1[4*rq+2] : acc0[4*rq+2]) * rl;
      const float a3 = (dt ? acc1[4*rq+3] : acc0[4*rq+3]) * rl;
      ushort4 st;
      st.x = f2bf(a0); st.y = f2bf(a1); st.z = f2bf(a2); st.w = f2bf(a3);
      *reinterpret_cast<ushort4*>(op + dt*32 + rq*8) = st;
    }
  }
}

// ---------------- launcher ----------------
extern "C" void kernel_launch(void* const* d_in, const int* in_sizes, int n_in,
                              void* d_out, int out_size, void* d_ws, size_t ws_size,
                              hipStream_t stream) {
  const float* x    = (const float*)d_in[0];
  const float* cosT = (const float*)d_in[1];
  const float* sinT = (const float*)d_in[2];
  const float* Wq   = (const float*)d_in[4];
  const float* Wk   = (const float*)d_in[5];
  const float* Wv   = (const float*)d_in[6];
  const float* Wo   = (const float*)d_in[7];
  float* out = (float*)d_out;

  char* ws = (char*)d_ws;
  unsigned short* xb     = (unsigned short*)(ws);              // 16 MB; reused as ctxb
  unsigned short* ctxb   = xb;
  unsigned short* Wqkv_t = (unsigned short*)(ws + 16777216);   // 12.58 MB; reused as Kp
  unsigned short* Kp     = Wqkv_t;                             // 4 MB (after GEMM)
  unsigned short* Wo_t   = (unsigned short*)(ws + 29360128);   // 8 MB
  unsigned short* QKVb   = (unsigned short*)(ws + 37748736);   // 4096*2560*2 = 20.97 MB
  unsigned short* Vp     = (unsigned short*)(ws + 58720256);   // 4 MB -> ends 62,914,560

  k_cvt<<<dim3(M_*DIN/4/256), dim3(256), 0, stream>>>(x, xb, M_*DIN/4);

  dim3 tb(32, 8);
  k_transpose<<<dim3(DOUT/32, DIN/32), tb, 0, stream>>>(Wq, Wqkv_t, DIN, DOUT);
  k_transpose<<<dim3(512/32,  DIN/32), tb, 0, stream>>>(Wk, Wqkv_t + (size_t)2048*DIN, DIN, 512);
  k_transpose<<<dim3(512/32,  DIN/32), tb, 0, stream>>>(Wv, Wqkv_t + (size_t)2560*DIN, DIN, 512);
  k_transpose<<<dim3(DOUT/32, DOUT/32), tb, 0, stream>>>(Wo, Wo_t, DOUT, DOUT);

  // fused QKV projection: 768 blocks (3/CU); V diverted to fragment-linear Vp
  k_gemm_bt<unsigned short, true><<<dim3(3072/128, M_/128), 256, 0, stream>>>(
      xb, Wqkv_t, QKVb, Vp, M_, 3072, QKS, DIN);

  const float QSCALE = 0.125f * 1.44269504088896f;   // 1/sqrt(64) * log2(e)
  k_rope<<<dim3(M_*H_*32/256), dim3(256), 0, stream>>>(QKVb, cosT, sinT, H_, QKS, QSCALE);
  k_rope<<<dim3(M_*G_*32/256), dim3(256), 0, stream>>>(QKVb + 2048, cosT, sinT, G_, QKS, 1.0f);

  k_pack<<<dim3(64, 16), dim3(64), 0, stream>>>(QKVb, Kp);

  k_attn<<<dim3(1024), dim3(256), 0, stream>>>(QKVb, Kp, Vp, ctxb);

  k_gemm_bt<float, false><<<dim3(DOUT/128, M_/128), 256, 0, stream>>>(
      ctxb, Wo_t, out, nullptr, M_, DOUT, DOUT, DIN);
}

// Round 10
// 239.802 us; speedup vs baseline: 1.1130x; 1.0106x over previous
//
#include <hip/hip_runtime.h>
#include <hip/hip_bf16.h>
#include <stdint.h>

#define B_   2
#define N_   2048
#define DIN  2048
#define DOUT 2048
#define H_   32
#define G_   8
#define HD_  64
#define M_   (B_*N_)   // 4096

using short8 = __attribute__((ext_vector_type(8))) short;
using f32x4  = __attribute__((ext_vector_type(4))) float;
using f32x16 = __attribute__((ext_vector_type(16))) float;
using int4v  = __attribute__((ext_vector_type(4))) int;

__device__ __forceinline__ unsigned short f2bf(float f) {
  unsigned int u = __float_as_uint(f);
  unsigned int r = u + 0x7FFFu + ((u >> 16) & 1u);
  return (unsigned short)(r >> 16);
}
__device__ __forceinline__ float bf2f(unsigned short h) {
  return __uint_as_float(((unsigned int)h) << 16);
}

// ---------------- elementwise f32 -> bf16 (4 elems/thread) ----------------
__global__ void k_cvt(const float* __restrict__ in, unsigned short* __restrict__ out, int n4) {
  int i = blockIdx.x * 256 + threadIdx.x;
  if (i >= n4) return;
  float4 v = reinterpret_cast<const float4*>(in)[i];
  uint2 o;
  o.x = (unsigned int)f2bf(v.x) | ((unsigned int)f2bf(v.y) << 16);
  o.y = (unsigned int)f2bf(v.z) | ((unsigned int)f2bf(v.w) << 16);
  reinterpret_cast<uint2*>(out)[i] = o;
}

// ---------------- transpose + convert: W (R x C) f32 -> Wt (C x R) bf16 ----------------
__global__ void k_transpose(const float* __restrict__ W, unsigned short* __restrict__ Wt,
                            int R, int C) {
  __shared__ float tile[32][33];
  int c0 = blockIdx.x * 32, r0 = blockIdx.y * 32;
  int tx = threadIdx.x, ty = threadIdx.y;  // (32,8)
  #pragma unroll
  for (int j = 0; j < 4; ++j)
    tile[ty + j*8][tx] = W[(size_t)(r0 + ty + j*8) * C + c0 + tx];
  __syncthreads();
  #pragma unroll
  for (int j = 0; j < 4; ++j)
    Wt[(size_t)(c0 + ty + j*8) * R + r0 + tx] = f2bf(tile[tx][ty + j*8]);
}

// ---------------- fused QKV GEMM: x @ [Wq|Wk|Wv]^T with RoPE epilogue ----------------
// 128x128 tile, BK=32, m97 staging structure, T1 bijective XCD swizzle.
// Epilogue by column tile:
//   cols [0,2048)    : Q  -> RoPE * (0.125*log2e) -> fragment-linear Qp[(b*32+h)*64+t]
//   cols [2048,2560) : K  -> RoPE                 -> fragment-linear Kp[(b*8+g)*64+t]
//   cols [2560,3072) : V  ->                         fragment-linear Vp[(b*8+g)*64+t]
// Fragment-linear tile layout (2048 elems): consumed by k_attn as 4x contiguous 1KB loads.
//   Q/K: elem(key,e) at (e>>4)*512 + ((e>>3)&1)*256 + (key&31)*8 + (e&7)
//   V  : elem(key,d) at (d>>5)*1024 + ((key>>4)&1)*512 + ((key>>3)&1)*256 + (d&31)*8 + (key&7)
__global__ void __launch_bounds__(256)
k_gemm_qkv(const unsigned short* __restrict__ A, const unsigned short* __restrict__ Bt,
           unsigned short* __restrict__ Qp, unsigned short* __restrict__ Kp,
           unsigned short* __restrict__ Vp,
           const float* __restrict__ cosT, const float* __restrict__ sinT) {
  __shared__ unsigned short As[128 * 32];
  __shared__ unsigned short Bs[128 * 32];
  const int K = DIN;
  const int tid  = threadIdx.x;
  const int wid  = tid >> 6, l = tid & 63;
  const int lrow = l & 15,  lk = l >> 4;
  const int wm = wid >> 1,  wn = wid & 1;

  const int gx   = gridDim.x;
  const int nwg  = gx * gridDim.y;
  const int orig = blockIdx.y * gx + blockIdx.x;
  const int q8   = nwg >> 3;
  const int xcd  = orig & 7, lin = orig >> 3;
  const int wg   = xcd * q8 + lin;            // nwg % 8 == 0 here
  const int bx   = wg % gx, by = wg / gx;

  const int rowA0 = by * 128, rowB0 = bx * 128;

  f32x4 acc[4][4];
  #pragma unroll
  for (int m = 0; m < 4; ++m)
    #pragma unroll
    for (int n = 0; n < 4; ++n)
      #pragma unroll
      for (int r = 0; r < 4; ++r) acc[m][n][r] = 0.f;

  int srow[2], scol[2];
  #pragma unroll
  for (int issue = 0; issue < 2; ++issue) {
    int slot = issue*4096 + wid*1024 + l*16;
    int row  = slot >> 6;
    int cp   = (slot >> 4) & 3;
    int sw   = (row & 3) ^ ((row >> 2) & 3);
    srow[issue] = row;
    scol[issue] = (cp ^ sw) * 8;
  }
  const int swr    = (lrow & 3) ^ ((lrow >> 2) & 3);
  const int rchunk = (lk ^ swr) * 8;

  for (int kt = 0; kt < K; kt += 32) {
    __syncthreads();
    #pragma unroll
    for (int issue = 0; issue < 2; ++issue) {
      const unsigned short* ga = A  + (size_t)(rowA0 + srow[issue]) * K + kt + scol[issue];
      const unsigned short* gb = Bt + (size_t)(rowB0 + srow[issue]) * K + kt + scol[issue];
      __builtin_amdgcn_global_load_lds(
          (const __attribute__((address_space(1))) unsigned int*)ga,
          (__attribute__((address_space(3))) unsigned int*)((char*)As + issue*4096 + wid*1024),
          16, 0, 0);
      __builtin_amdgcn_global_load_lds(
          (const __attribute__((address_space(1))) unsigned int*)gb,
          (__attribute__((address_space(3))) unsigned int*)((char*)Bs + issue*4096 + wid*1024),
          16, 0, 0);
    }
    asm volatile("s_waitcnt vmcnt(0)" ::: "memory");
    __syncthreads();

    short8 av[4], bv[4];
    #pragma unroll
    for (int m = 0; m < 4; ++m)
      av[m] = *reinterpret_cast<const short8*>(&As[(wm*64 + m*16 + lrow)*32 + rchunk]);
    #pragma unroll
    for (int n = 0; n < 4; ++n)
      bv[n] = *reinterpret_cast<const short8*>(&Bs[(wn*64 + n*16 + lrow)*32 + rchunk]);
    #pragma unroll
    for (int m = 0; m < 4; ++m)
      #pragma unroll
      for (int n = 0; n < 4; ++n)
        acc[m][n] = __builtin_amdgcn_mfma_f32_16x16x32_bf16(av[m], bv[n], acc[m][n], 0, 0, 0);
  }

  if (rowB0 >= 2560) {
    // ---- V: direct fragment-linear Vp write (r9-proven) ----
    const int bq = rowA0 >> 11;
    #pragma unroll
    for (int m = 0; m < 4; ++m) {
      const int row0 = rowA0 + wm*64 + m*16 + lk*4;
      const int key  = row0 & 2047;
      const size_t tbase = (size_t)(key >> 5)*2048 + (size_t)((key >> 4) & 1)*512
                         + (size_t)((key >> 3) & 1)*256 + (size_t)(key & 7);
      #pragma unroll
      for (int n = 0; n < 4; ++n) {
        const int cv = rowB0 + wn*64 + n*16 + lrow - 2560;
        const int gq = cv >> 6, d = cv & 63;
        const size_t addr = (size_t)(bq*8 + gq)*131072 + tbase
                          + (size_t)(d >> 5)*1024 + (size_t)(d & 31)*8;
        ushort4 st;
        st.x = f2bf(acc[m][n][0]); st.y = f2bf(acc[m][n][1]);
        st.z = f2bf(acc[m][n][2]); st.w = f2bf(acc[m][n][3]);
        *reinterpret_cast<ushort4*>(Vp + addr) = st;
      }
    }
  } else {
    // ---- Q or K: fused RoPE on in-lane pairs (acc[m][n], acc[m][n+2]), scatter ----
    const bool isQ = (rowB0 < 2048);
    const float scale = isQ ? 0.18033688011112042f : 1.0f;   // 0.125 * log2(e)
    unsigned short* dst = isQ ? Qp : Kp;
    #pragma unroll
    for (int m = 0; m < 4; ++m) {
      const int row0 = rowA0 + wm*64 + m*16 + lk*4;
      const int b = row0 >> 11;
      #pragma unroll
      for (int n = 0; n < 2; ++n) {
        const int col = rowB0 + wn*64 + n*16 + lrow;
        const int e   = n*16 + lrow;               // head-relative d, < 32
        const int hg  = isQ ? (col >> 6) : ((col - 2048) >> 6);
        const size_t chunk = (size_t)(isQ ? (b*32 + hg) : (b*8 + hg)) * 64;
        #pragma unroll
        for (int r = 0; r < 4; ++r) {
          const int pos = (row0 + r) & 2047;
          const float cc = cosT[pos*64 + e] * scale;
          const float ss = sinT[pos*64 + e] * scale;
          const float x1 = acc[m][n][r];
          const float x2 = acc[m][n+2][r];
          const size_t off = (chunk + (pos >> 5)) * 2048
                           + (size_t)(e >> 4)*512 + (size_t)((e >> 3) & 1)*256
                           + (size_t)(pos & 31)*8 + (e & 7);
          dst[off]        = f2bf(x1*cc - x2*ss);
          dst[off + 1024] = f2bf(x2*cc + x1*ss);    // e+32: c -> c+2 = +1024 elems
        }
      }
    }
  }
}

// ---------------- output GEMM: ctx @ Wo^T -> f32 out ----------------
__global__ void __launch_bounds__(256)
k_gemm_out(const unsigned short* __restrict__ A, const unsigned short* __restrict__ Bt,
           float* __restrict__ C) {
  __shared__ unsigned short As[128 * 32];
  __shared__ unsigned short Bs[128 * 32];
  const int K = DOUT, N = DOUT;
  const int tid  = threadIdx.x;
  const int wid  = tid >> 6, l = tid & 63;
  const int lrow = l & 15,  lk = l >> 4;
  const int wm = wid >> 1,  wn = wid & 1;

  const int gx   = gridDim.x;
  const int nwg  = gx * gridDim.y;
  const int orig = blockIdx.y * gx + blockIdx.x;
  const int q8   = nwg >> 3;
  const int xcd  = orig & 7, lin = orig >> 3;
  const int wg   = xcd * q8 + lin;
  const int bx   = wg % gx, by = wg / gx;

  const int rowA0 = by * 128, rowB0 = bx * 128;

  f32x4 acc[4][4];
  #pragma unroll
  for (int m = 0; m < 4; ++m)
    #pragma unroll
    for (int n = 0; n < 4; ++n)
      #pragma unroll
      for (int r = 0; r < 4; ++r) acc[m][n][r] = 0.f;

  int srow[2], scol[2];
  #pragma unroll
  for (int issue = 0; issue < 2; ++issue) {
    int slot = issue*4096 + wid*1024 + l*16;
    int row  = slot >> 6;
    int cp   = (slot >> 4) & 3;
    int sw   = (row & 3) ^ ((row >> 2) & 3);
    srow[issue] = row;
    scol[issue] = (cp ^ sw) * 8;
  }
  const int swr    = (lrow & 3) ^ ((lrow >> 2) & 3);
  const int rchunk = (lk ^ swr) * 8;

  for (int kt = 0; kt < K; kt += 32) {
    __syncthreads();
    #pragma unroll
    for (int issue = 0; issue < 2; ++issue) {
      const unsigned short* ga = A  + (size_t)(rowA0 + srow[issue]) * K + kt + scol[issue];
      const unsigned short* gb = Bt + (size_t)(rowB0 + srow[issue]) * K + kt + scol[issue];
      __builtin_amdgcn_global_load_lds(
          (const __attribute__((address_space(1))) unsigned int*)ga,
          (__attribute__((address_space(3))) unsigned int*)((char*)As + issue*4096 + wid*1024),
          16, 0, 0);
      __builtin_amdgcn_global_load_lds(
          (const __attribute__((address_space(1))) unsigned int*)gb,
          (__attribute__((address_space(3))) unsigned int*)((char*)Bs + issue*4096 + wid*1024),
          16, 0, 0);
    }
    asm volatile("s_waitcnt vmcnt(0)" ::: "memory");
    __syncthreads();

    short8 av[4], bv[4];
    #pragma unroll
    for (int m = 0; m < 4; ++m)
      av[m] = *reinterpret_cast<const short8*>(&As[(wm*64 + m*16 + lrow)*32 + rchunk]);
    #pragma unroll
    for (int n = 0; n < 4; ++n)
      bv[n] = *reinterpret_cast<const short8*>(&Bs[(wn*64 + n*16 + lrow)*32 + rchunk]);
    #pragma unroll
    for (int m = 0; m < 4; ++m)
      #pragma unroll
      for (int n = 0; n < 4; ++n)
        acc[m][n] = __builtin_amdgcn_mfma_f32_16x16x32_bf16(av[m], bv[n], acc[m][n], 0, 0, 0);
  }

  #pragma unroll
  for (int m = 0; m < 4; ++m) {
    int row0 = rowA0 + wm*64 + m*16 + lk*4;
    #pragma unroll
    for (int n = 0; n < 4; ++n) {
      int col = rowB0 + wn*64 + n*16 + lrow;
      #pragma unroll
      for (int r = 0; r < 4; ++r)
        C[(size_t)(row0 + r) * N + col] = acc[m][n][r];
    }
  }
}

// ---------------- causal GQA flash attention (r8-proven structure) ----------------
// 4-wave blocks (4 heads of one (b,g,qt)); K/V staged in shared LDS via
// global_load_lds (fragment-linear), double-buffered, one barrier per tile.
// Q from fragment-linear Qp (4 contiguous 1KB loads). T5 setprio; T13 defer-max;
// T12 permlane32_swap P-pack.
__global__ void __launch_bounds__(256, 3)
k_attn(const unsigned short* __restrict__ Qp, const unsigned short* __restrict__ Kp,
       const unsigned short* __restrict__ Vp, unsigned short* __restrict__ ctx) {
  __shared__ unsigned short kvlds[2][4096];   // [buf][ K:0..2047 | V:2048..4095 ]
  const int bid = blockIdx.x;            // 0..1023
  const int c   = bid & 15;              // (b,g) chunk -> fixed XCD
  const int b   = c >> 3, g = c & 7;
  const int qt  = 63 - (bid >> 4);       // longest first
  const int tid = threadIdx.x;
  const int hh  = tid >> 6;              // wave id = head within group
  const int h   = g*4 + hh;
  const int l   = tid & 63;
  const int lq  = l & 31, hi = l >> 5;

  const unsigned short* qbase = Qp + ((size_t)(b*32 + h)*64 + qt)*2048 + l*8;
  short8 qf0 = *reinterpret_cast<const short8*>(qbase);
  short8 qf1 = *reinterpret_cast<const short8*>(qbase + 512);
  short8 qf2 = *reinterpret_cast<const short8*>(qbase + 1024);
  short8 qf3 = *reinterpret_cast<const short8*>(qbase + 1536);

  const unsigned short* ksrc = Kp + (size_t)c*131072 + hh*512 + l*8;
  const unsigned short* vsrc = Vp + (size_t)c*131072 + hh*512 + l*8;

  f32x16 acc0, acc1;
  #pragma unroll
  for (int r = 0; r < 16; ++r) { acc0[r] = 0.f; acc1[r] = 0.f; }
  float m_run = -3.0e38f, l_run = 0.f;

  auto stage = [&](int t, int buf) {
    __builtin_amdgcn_global_load_lds(
        (const __attribute__((address_space(1))) unsigned int*)(ksrc + (size_t)t*2048),
        (__attribute__((address_space(3))) unsigned int*)((char*)&kvlds[buf][0] + hh*1024),
        16, 0, 0);
    __builtin_amdgcn_global_load_lds(
        (const __attribute__((address_space(1))) unsigned int*)(vsrc + (size_t)t*2048),
        (__attribute__((address_space(3))) unsigned int*)((char*)&kvlds[buf][2048] + hh*1024),
        16, 0, 0);
  };

  auto body = [&](bool diag, int buf) {
    short8 ka = *reinterpret_cast<const short8*>(&kvlds[buf][l*8]);
    short8 kb = *reinterpret_cast<const short8*>(&kvlds[buf][512 + l*8]);
    short8 kc = *reinterpret_cast<const short8*>(&kvlds[buf][1024 + l*8]);
    short8 kd = *reinterpret_cast<const short8*>(&kvlds[buf][1536 + l*8]);

    f32x16 s;
    #pragma unroll
    for (int r = 0; r < 16; ++r) s[r] = 0.f;
    __builtin_amdgcn_s_setprio(1);
    s = __builtin_amdgcn_mfma_f32_32x32x16_bf16(ka, qf0, s, 0, 0, 0);
    s = __builtin_amdgcn_mfma_f32_32x32x16_bf16(kb, qf1, s, 0, 0, 0);
    s = __builtin_amdgcn_mfma_f32_32x32x16_bf16(kc, qf2, s, 0, 0, 0);
    s = __builtin_amdgcn_mfma_f32_32x32x16_bf16(kd, qf3, s, 0, 0, 0);
    __builtin_amdgcn_s_setprio(0);

    if (diag) {
      #pragma unroll
      for (int r = 0; r < 16; ++r) {
        const int ko = (r & 3) + 8*(r >> 2) + 4*hi;
        s[r] = (ko <= lq) ? s[r] : -3.0e38f;
      }
    }
    float t0 = fmaxf(fmaxf(s[0], s[1]), s[2]);
    float t1 = fmaxf(fmaxf(s[3], s[4]), s[5]);
    float t2 = fmaxf(fmaxf(s[6], s[7]), s[8]);
    float t3 = fmaxf(fmaxf(s[9], s[10]), s[11]);
    float t4 = fmaxf(fmaxf(s[12], s[13]), s[14]);
    float mt = fmaxf(fmaxf(fmaxf(t0, t1), fmaxf(t2, t3)), fmaxf(t4, s[15]));
    mt = fmaxf(mt, __shfl_xor(mt, 32));
    if (!__all(mt <= m_run + 8.f)) {          // T13 defer-max
      float nm = fmaxf(m_run, mt);
      float fr = exp2f(m_run - nm);
      m_run = nm;
      l_run *= fr;
      #pragma unroll
      for (int r = 0; r < 16; ++r) { acc0[r] *= fr; acc1[r] *= fr; }
    }
    unsigned int w[8];
    float ps = 0.f;
    #pragma unroll
    for (int i = 0; i < 8; ++i) {
      float p0 = exp2f(s[2*i]   - m_run);
      float p1 = exp2f(s[2*i+1] - m_run);
      ps += p0 + p1;
      asm("v_cvt_pk_bf16_f32 %0, %1, %2" : "=v"(w[i]) : "v"(p0), "v"(p1));
    }
    ps += __shfl_xor(ps, 32);
    l_run += ps;

    // T12: permlane32_swap builds both halves of each P fragment word
    unsigned int x0 = w[0], x1 = w[1], y0 = w[2], y1 = w[3];
    asm("v_permlane32_swap_b32 %0, %1" : "+v"(x0), "+v"(y0));
    asm("v_permlane32_swap_b32 %0, %1" : "+v"(x1), "+v"(y1));
    unsigned int x2 = w[4], x3 = w[5], y2 = w[6], y3 = w[7];
    asm("v_permlane32_swap_b32 %0, %1" : "+v"(x2), "+v"(y2));
    asm("v_permlane32_swap_b32 %0, %1" : "+v"(x3), "+v"(y3));
    int4v p0i, p1i;
    p0i[0] = (int)x0; p0i[1] = (int)x1; p0i[2] = (int)y0; p0i[3] = (int)y1;
    p1i[0] = (int)x2; p1i[1] = (int)x3; p1i[2] = (int)y2; p1i[3] = (int)y3;
    short8 pa0 = __builtin_bit_cast(short8, p0i);
    short8 pa1 = __builtin_bit_cast(short8, p1i);

    short8 va = *reinterpret_cast<const short8*>(&kvlds[buf][2048 + l*8]);
    short8 vb = *reinterpret_cast<const short8*>(&kvlds[buf][2560 + l*8]);
    short8 vc = *reinterpret_cast<const short8*>(&kvlds[buf][3072 + l*8]);
    short8 vd = *reinterpret_cast<const short8*>(&kvlds[buf][3584 + l*8]);

    __builtin_amdgcn_s_setprio(1);
    acc0 = __builtin_amdgcn_mfma_f32_32x32x16_bf16(va, pa0, acc0, 0, 0, 0);
    acc0 = __builtin_amdgcn_mfma_f32_32x32x16_bf16(vb, pa1, acc0, 0, 0, 0);
    acc1 = __builtin_amdgcn_mfma_f32_32x32x16_bf16(vc, pa0, acc1, 0, 0, 0);
    acc1 = __builtin_amdgcn_mfma_f32_32x32x16_bf16(vd, pa1, acc1, 0, 0, 0);
    __builtin_amdgcn_s_setprio(0);
  };

  stage(0, 0);
  __syncthreads();
  for (int t = 0; ; ) {
    const int cur = t & 1;
    if (t < qt) stage(t + 1, cur ^ 1);   // issue-early: latency hides under compute
    body(t == qt, cur);
    if (++t > qt) break;
    __syncthreads();                     // drains vmcnt (stage done) + lgkm (reads done)
  }

  const float rl = 1.f / l_run;
  unsigned short* op = ctx + (size_t)(b*N_ + qt*32 + lq) * DOUT + h*HD_ + 4*hi;
  #pragma unroll
  for (int dt = 0; dt < 2; ++dt) {
    #pragma unroll
    for (int rq = 0; rq < 4; ++rq) {
      const float a0 = (dt ? acc1[4*rq+0] : acc0[4*rq+0]) * rl;
      const float a1 = (dt ? acc1[4*rq+1] : acc0[4*rq+1]) * rl;
      const float a2 = (dt ? acc1[4*rq+2] : acc0[4*rq+2]) * rl;
      const float a3 = (dt ? acc1[4*rq+3] : acc0[4*rq+3]) * rl;
      ushort4 st;
      st.x = f2bf(a0); st.y = f2bf(a1); st.z = f2bf(a2); st.w = f2bf(a3);
      *reinterpret_cast<ushort4*>(op + dt*32 + rq*8) = st;
    }
  }
}

// ---------------- launcher ----------------
extern "C" void kernel_launch(void* const* d_in, const int* in_sizes, int n_in,
                              void* d_out, int out_size, void* d_ws, size_t ws_size,
                              hipStream_t stream) {
  const float* x    = (const float*)d_in[0];
  const float* cosT = (const float*)d_in[1];
  const float* sinT = (const float*)d_in[2];
  const float* Wq   = (const float*)d_in[4];
  const float* Wk   = (const float*)d_in[5];
  const float* Wv   = (const float*)d_in[6];
  const float* Wo   = (const float*)d_in[7];
  float* out = (float*)d_out;

  char* ws = (char*)d_ws;
  unsigned short* xb     = (unsigned short*)(ws);              // 16.78 MB; reused as ctxb
  unsigned short* ctxb   = xb;
  unsigned short* Wqkv_t = (unsigned short*)(ws + 16777216);   // 12.58 MB (3072 x 2048)
  unsigned short* Wo_t   = (unsigned short*)(ws + 29360128);   //  8.39 MB
  unsigned short* Qp     = (unsigned short*)(ws + 37748736);   // 16.78 MB
  unsigned short* Kp     = (unsigned short*)(ws + 54525952);   //  4.19 MB
  unsigned short* Vp     = (unsigned short*)(ws + 58720256);   //  4.19 MB -> 62,914,560 total

  k_cvt<<<dim3(M_*DIN/4/256), dim3(256), 0, stream>>>(x, xb, M_*DIN/4);

  dim3 tb(32, 8);
  k_transpose<<<dim3(DOUT/32, DIN/32), tb, 0, stream>>>(Wq, Wqkv_t, DIN, DOUT);
  k_transpose<<<dim3(512/32,  DIN/32), tb, 0, stream>>>(Wk, Wqkv_t + (size_t)2048*DIN, DIN, 512);
  k_transpose<<<dim3(512/32,  DIN/32), tb, 0, stream>>>(Wv, Wqkv_t + (size_t)2560*DIN, DIN, 512);
  k_transpose<<<dim3(DOUT/32, DOUT/32), tb, 0, stream>>>(Wo, Wo_t, DOUT, DOUT);

  // fused QKV projection + RoPE + fragment-linear Q/K/V emission (no QKV buffer)
  k_gemm_qkv<<<dim3(3072/128, M_/128), 256, 0, stream>>>(
      xb, Wqkv_t, Qp, Kp, Vp, cosT, sinT);

  k_attn<<<dim3(1024), dim3(256), 0, stream>>>(Qp, Kp, Vp, ctxb);

  k_gemm_out<<<dim3(DOUT/128, M_/128), 256, 0, stream>>>(ctxb, Wo_t, out);
}

// Round 11
// 207.016 us; speedup vs baseline: 1.2893x; 1.1584x over previous
//
#include <hip/hip_runtime.h>
#include <hip/hip_bf16.h>
#include <stdint.h>

#define B_   2
#define N_   2048
#define DIN  2048
#define DOUT 2048
#define H_   32
#define G_   8
#define HD_  64
#define M_   (B_*N_)   // 4096

using short8 = __attribute__((ext_vector_type(8))) short;
using f32x4  = __attribute__((ext_vector_type(4))) float;
using f32x16 = __attribute__((ext_vector_type(16))) float;
using int4v  = __attribute__((ext_vector_type(4))) int;

__device__ __forceinline__ unsigned short f2bf(float f) {
  unsigned int u = __float_as_uint(f);
  unsigned int r = u + 0x7FFFu + ((u >> 16) & 1u);
  return (unsigned short)(r >> 16);
}
__device__ __forceinline__ float bf2f(unsigned short h) {
  return __uint_as_float(((unsigned int)h) << 16);
}

// ---------------- elementwise f32 -> bf16 (4 elems/thread) ----------------
__global__ void k_cvt(const float* __restrict__ in, unsigned short* __restrict__ out, int n4) {
  int i = blockIdx.x * 256 + threadIdx.x;
  if (i >= n4) return;
  float4 v = reinterpret_cast<const float4*>(in)[i];
  uint2 o;
  o.x = (unsigned int)f2bf(v.x) | ((unsigned int)f2bf(v.y) << 16);
  o.y = (unsigned int)f2bf(v.z) | ((unsigned int)f2bf(v.w) << 16);
  reinterpret_cast<uint2*>(out)[i] = o;
}

// ---------------- transpose + convert: W (R x C) f32 -> Wt (C x R) bf16 ----------------
__global__ void k_transpose(const float* __restrict__ W, unsigned short* __restrict__ Wt,
                            int R, int C) {
  __shared__ float tile[32][33];
  int c0 = blockIdx.x * 32, r0 = blockIdx.y * 32;
  int tx = threadIdx.x, ty = threadIdx.y;  // (32,8)
  #pragma unroll
  for (int j = 0; j < 4; ++j)
    tile[ty + j*8][tx] = W[(size_t)(r0 + ty + j*8) * C + c0 + tx];
  __syncthreads();
  #pragma unroll
  for (int j = 0; j < 4; ++j)
    Wt[(size_t)(c0 + ty + j*8) * R + r0 + tx] = f2bf(tile[tx][ty + j*8]);
}

// ---------------- fused QKV GEMM: x @ [Wq|Wk|Wv]^T with RoPE epilogue ----------------
// 128x128 tile, BK=32, m97 staging, T1 XCD swizzle. launch_bounds(256,3) pins the
// unified reg budget to the m97 level (3 blocks/CU) — r10's 180-reg epilogue bloat
// dropped co-residency to 2 and stalled both pipes (VALUBusy 10%).
__global__ void __launch_bounds__(256, 3)
k_gemm_qkv(const unsigned short* __restrict__ A, const unsigned short* __restrict__ Bt,
           unsigned short* __restrict__ Qp, unsigned short* __restrict__ Kp,
           unsigned short* __restrict__ Vp,
           const float* __restrict__ cosT, const float* __restrict__ sinT) {
  __shared__ unsigned short As[128 * 32];
  __shared__ unsigned short Bs[128 * 32];
  const int K = DIN;
  const int tid  = threadIdx.x;
  const int wid  = tid >> 6, l = tid & 63;
  const int lrow = l & 15,  lk = l >> 4;
  const int wm = wid >> 1,  wn = wid & 1;

  const int gx   = gridDim.x;
  const int nwg  = gx * gridDim.y;
  const int orig = blockIdx.y * gx + blockIdx.x;
  const int q8   = nwg >> 3;
  const int xcd  = orig & 7, lin = orig >> 3;
  const int wg   = xcd * q8 + lin;            // nwg % 8 == 0 here
  const int bx   = wg % gx, by = wg / gx;

  const int rowA0 = by * 128, rowB0 = bx * 128;

  f32x4 acc[4][4];
  #pragma unroll
  for (int m = 0; m < 4; ++m)
    #pragma unroll
    for (int n = 0; n < 4; ++n)
      #pragma unroll
      for (int r = 0; r < 4; ++r) acc[m][n][r] = 0.f;

  int srow[2], scol[2];
  #pragma unroll
  for (int issue = 0; issue < 2; ++issue) {
    int slot = issue*4096 + wid*1024 + l*16;
    int row  = slot >> 6;
    int cp   = (slot >> 4) & 3;
    int sw   = (row & 3) ^ ((row >> 2) & 3);
    srow[issue] = row;
    scol[issue] = (cp ^ sw) * 8;
  }
  const int swr    = (lrow & 3) ^ ((lrow >> 2) & 3);
  const int rchunk = (lk ^ swr) * 8;

  for (int kt = 0; kt < K; kt += 32) {
    __syncthreads();
    #pragma unroll
    for (int issue = 0; issue < 2; ++issue) {
      const unsigned short* ga = A  + (size_t)(rowA0 + srow[issue]) * K + kt + scol[issue];
      const unsigned short* gb = Bt + (size_t)(rowB0 + srow[issue]) * K + kt + scol[issue];
      __builtin_amdgcn_global_load_lds(
          (const __attribute__((address_space(1))) unsigned int*)ga,
          (__attribute__((address_space(3))) unsigned int*)((char*)As + issue*4096 + wid*1024),
          16, 0, 0);
      __builtin_amdgcn_global_load_lds(
          (const __attribute__((address_space(1))) unsigned int*)gb,
          (__attribute__((address_space(3))) unsigned int*)((char*)Bs + issue*4096 + wid*1024),
          16, 0, 0);
    }
    asm volatile("s_waitcnt vmcnt(0)" ::: "memory");
    __syncthreads();

    short8 av[4], bv[4];
    #pragma unroll
    for (int m = 0; m < 4; ++m)
      av[m] = *reinterpret_cast<const short8*>(&As[(wm*64 + m*16 + lrow)*32 + rchunk]);
    #pragma unroll
    for (int n = 0; n < 4; ++n)
      bv[n] = *reinterpret_cast<const short8*>(&Bs[(wn*64 + n*16 + lrow)*32 + rchunk]);
    #pragma unroll
    for (int m = 0; m < 4; ++m)
      #pragma unroll
      for (int n = 0; n < 4; ++n)
        acc[m][n] = __builtin_amdgcn_mfma_f32_16x16x32_bf16(av[m], bv[n], acc[m][n], 0, 0, 0);
  }

  if (rowB0 >= 2560) {
    // ---- V: direct fragment-linear Vp write (r9-proven) ----
    const int bq = rowA0 >> 11;
    #pragma unroll
    for (int m = 0; m < 4; ++m) {
      const int row0 = rowA0 + wm*64 + m*16 + lk*4;
      const int key  = row0 & 2047;
      const size_t tbase = (size_t)(key >> 5)*2048 + (size_t)((key >> 4) & 1)*512
                         + (size_t)((key >> 3) & 1)*256 + (size_t)(key & 7);
      #pragma unroll
      for (int n = 0; n < 4; ++n) {
        const int cv = rowB0 + wn*64 + n*16 + lrow - 2560;
        const int gq = cv >> 6, d = cv & 63;
        const size_t addr = (size_t)(bq*8 + gq)*131072 + tbase
                          + (size_t)(d >> 5)*1024 + (size_t)(d & 31)*8;
        ushort4 st;
        st.x = f2bf(acc[m][n][0]); st.y = f2bf(acc[m][n][1]);
        st.z = f2bf(acc[m][n][2]); st.w = f2bf(acc[m][n][3]);
        *reinterpret_cast<ushort4*>(Vp + addr) = st;
      }
    }
  } else {
    // ---- Q or K: fused RoPE on in-lane pairs (acc[m][n], acc[m][n+2]), scatter ----
    const bool isQ = (rowB0 < 2048);
    const float scale = isQ ? 0.18033688011112042f : 1.0f;   // 0.125 * log2(e)
    unsigned short* dst = isQ ? Qp : Kp;
    #pragma unroll
    for (int m = 0; m < 4; ++m) {
      const int row0 = rowA0 + wm*64 + m*16 + lk*4;
      const int b = row0 >> 11;
      #pragma unroll
      for (int n = 0; n < 2; ++n) {
        const int col = rowB0 + wn*64 + n*16 + lrow;
        const int e   = n*16 + lrow;               // head-relative d, < 32
        const int hg  = isQ ? (col >> 6) : ((col - 2048) >> 6);
        const size_t chunk = (size_t)(isQ ? (b*32 + hg) : (b*8 + hg)) * 64;
        #pragma unroll
        for (int r = 0; r < 4; ++r) {
          const int pos = (row0 + r) & 2047;
          const float cc = cosT[pos*64 + e] * scale;
          const float ss = sinT[pos*64 + e] * scale;
          const float x1 = acc[m][n][r];
          const float x2 = acc[m][n+2][r];
          const size_t off = (chunk + (pos >> 5)) * 2048
                           + (size_t)(e >> 4)*512 + (size_t)((e >> 3) & 1)*256
                           + (size_t)(pos & 31)*8 + (e & 7);
          dst[off]        = f2bf(x1*cc - x2*ss);
          dst[off + 1024] = f2bf(x2*cc + x1*ss);    // e+32: c -> c+2 = +1024 elems
        }
      }
    }
  }
}

// ---------------- output GEMM: ctx @ Wo^T -> f32 out ----------------
__global__ void __launch_bounds__(256, 3)
k_gemm_out(const unsigned short* __restrict__ A, const unsigned short* __restrict__ Bt,
           float* __restrict__ C) {
  __shared__ unsigned short As[128 * 32];
  __shared__ unsigned short Bs[128 * 32];
  const int K = DOUT, N = DOUT;
  const int tid  = threadIdx.x;
  const int wid  = tid >> 6, l = tid & 63;
  const int lrow = l & 15,  lk = l >> 4;
  const int wm = wid >> 1,  wn = wid & 1;

  const int gx   = gridDim.x;
  const int nwg  = gx * gridDim.y;
  const int orig = blockIdx.y * gx + blockIdx.x;
  const int q8   = nwg >> 3;
  const int xcd  = orig & 7, lin = orig >> 3;
  const int wg   = xcd * q8 + lin;
  const int bx   = wg % gx, by = wg / gx;

  const int rowA0 = by * 128, rowB0 = bx * 128;

  f32x4 acc[4][4];
  #pragma unroll
  for (int m = 0; m < 4; ++m)
    #pragma unroll
    for (int n = 0; n < 4; ++n)
      #pragma unroll
      for (int r = 0; r < 4; ++r) acc[m][n][r] = 0.f;

  int srow[2], scol[2];
  #pragma unroll
  for (int issue = 0; issue < 2; ++issue) {
    int slot = issue*4096 + wid*1024 + l*16;
    int row  = slot >> 6;
    int cp   = (slot >> 4) & 3;
    int sw   = (row & 3) ^ ((row >> 2) & 3);
    srow[issue] = row;
    scol[issue] = (cp ^ sw) * 8;
  }
  const int swr    = (lrow & 3) ^ ((lrow >> 2) & 3);
  const int rchunk = (lk ^ swr) * 8;

  for (int kt = 0; kt < K; kt += 32) {
    __syncthreads();
    #pragma unroll
    for (int issue = 0; issue < 2; ++issue) {
      const unsigned short* ga = A  + (size_t)(rowA0 + srow[issue]) * K + kt + scol[issue];
      const unsigned short* gb = Bt + (size_t)(rowB0 + srow[issue]) * K + kt + scol[issue];
      __builtin_amdgcn_global_load_lds(
          (const __attribute__((address_space(1))) unsigned int*)ga,
          (__attribute__((address_space(3))) unsigned int*)((char*)As + issue*4096 + wid*1024),
          16, 0, 0);
      __builtin_amdgcn_global_load_lds(
          (const __attribute__((address_space(1))) unsigned int*)gb,
          (__attribute__((address_space(3))) unsigned int*)((char*)Bs + issue*4096 + wid*1024),
          16, 0, 0);
    }
    asm volatile("s_waitcnt vmcnt(0)" ::: "memory");
    __syncthreads();

    short8 av[4], bv[4];
    #pragma unroll
    for (int m = 0; m < 4; ++m)
      av[m] = *reinterpret_cast<const short8*>(&As[(wm*64 + m*16 + lrow)*32 + rchunk]);
    #pragma unroll
    for (int n = 0; n < 4; ++n)
      bv[n] = *reinterpret_cast<const short8*>(&Bs[(wn*64 + n*16 + lrow)*32 + rchunk]);
    #pragma unroll
    for (int m = 0; m < 4; ++m)
      #pragma unroll
      for (int n = 0; n < 4; ++n)
        acc[m][n] = __builtin_amdgcn_mfma_f32_16x16x32_bf16(av[m], bv[n], acc[m][n], 0, 0, 0);
  }

  #pragma unroll
  for (int m = 0; m < 4; ++m) {
    int row0 = rowA0 + wm*64 + m*16 + lk*4;
    #pragma unroll
    for (int n = 0; n < 4; ++n) {
      int col = rowB0 + wn*64 + n*16 + lrow;
      #pragma unroll
      for (int r = 0; r < 4; ++r)
        C[(size_t)(row0 + r) * N + col] = acc[m][n][r];
    }
  }
}

// ---------------- causal GQA flash attention (r8-proven structure) ----------------
// 4-wave blocks (4 heads of one (b,g,qt)); K/V staged in shared LDS via
// global_load_lds (fragment-linear), double-buffered, one barrier per tile.
// Q from fragment-linear Qp (4 contiguous 1KB loads). T5 setprio; T13 defer-max;
// T12 permlane32_swap P-pack.
__global__ void __launch_bounds__(256, 3)
k_attn(const unsigned short* __restrict__ Qp, const unsigned short* __restrict__ Kp,
       const unsigned short* __restrict__ Vp, unsigned short* __restrict__ ctx) {
  __shared__ unsigned short kvlds[2][4096];   // [buf][ K:0..2047 | V:2048..4095 ]
  const int bid = blockIdx.x;            // 0..1023
  const int c   = bid & 15;              // (b,g) chunk -> fixed XCD
  const int b   = c >> 3, g = c & 7;
  const int qt  = 63 - (bid >> 4);       // longest first
  const int tid = threadIdx.x;
  const int hh  = tid >> 6;              // wave id = head within group
  const int h   = g*4 + hh;
  const int l   = tid & 63;
  const int lq  = l & 31, hi = l >> 5;

  const unsigned short* qbase = Qp + ((size_t)(b*32 + h)*64 + qt)*2048 + l*8;
  short8 qf0 = *reinterpret_cast<const short8*>(qbase);
  short8 qf1 = *reinterpret_cast<const short8*>(qbase + 512);
  short8 qf2 = *reinterpret_cast<const short8*>(qbase + 1024);
  short8 qf3 = *reinterpret_cast<const short8*>(qbase + 1536);

  const unsigned short* ksrc = Kp + (size_t)c*131072 + hh*512 + l*8;
  const unsigned short* vsrc = Vp + (size_t)c*131072 + hh*512 + l*8;

  f32x16 acc0, acc1;
  #pragma unroll
  for (int r = 0; r < 16; ++r) { acc0[r] = 0.f; acc1[r] = 0.f; }
  float m_run = -3.0e38f, l_run = 0.f;

  auto stage = [&](int t, int buf) {
    __builtin_amdgcn_global_load_lds(
        (const __attribute__((address_space(1))) unsigned int*)(ksrc + (size_t)t*2048),
        (__attribute__((address_space(3))) unsigned int*)((char*)&kvlds[buf][0] + hh*1024),
        16, 0, 0);
    __builtin_amdgcn_global_load_lds(
        (const __attribute__((address_space(1))) unsigned int*)(vsrc + (size_t)t*2048),
        (__attribute__((address_space(3))) unsigned int*)((char*)&kvlds[buf][2048] + hh*1024),
        16, 0, 0);
  };

  auto body = [&](bool diag, int buf) {
    short8 ka = *reinterpret_cast<const short8*>(&kvlds[buf][l*8]);
    short8 kb = *reinterpret_cast<const short8*>(&kvlds[buf][512 + l*8]);
    short8 kc = *reinterpret_cast<const short8*>(&kvlds[buf][1024 + l*8]);
    short8 kd = *reinterpret_cast<const short8*>(&kvlds[buf][1536 + l*8]);

    f32x16 s;
    #pragma unroll
    for (int r = 0; r < 16; ++r) s[r] = 0.f;
    __builtin_amdgcn_s_setprio(1);
    s = __builtin_amdgcn_mfma_f32_32x32x16_bf16(ka, qf0, s, 0, 0, 0);
    s = __builtin_amdgcn_mfma_f32_32x32x16_bf16(kb, qf1, s, 0, 0, 0);
    s = __builtin_amdgcn_mfma_f32_32x32x16_bf16(kc, qf2, s, 0, 0, 0);
    s = __builtin_amdgcn_mfma_f32_32x32x16_bf16(kd, qf3, s, 0, 0, 0);
    __builtin_amdgcn_s_setprio(0);

    if (diag) {
      #pragma unroll
      for (int r = 0; r < 16; ++r) {
        const int ko = (r & 3) + 8*(r >> 2) + 4*hi;
        s[r] = (ko <= lq) ? s[r] : -3.0e38f;
      }
    }
    float t0 = fmaxf(fmaxf(s[0], s[1]), s[2]);
    float t1 = fmaxf(fmaxf(s[3], s[4]), s[5]);
    float t2 = fmaxf(fmaxf(s[6], s[7]), s[8]);
    float t3 = fmaxf(fmaxf(s[9], s[10]), s[11]);
    float t4 = fmaxf(fmaxf(s[12], s[13]), s[14]);
    float mt = fmaxf(fmaxf(fmaxf(t0, t1), fmaxf(t2, t3)), fmaxf(t4, s[15]));
    mt = fmaxf(mt, __shfl_xor(mt, 32));
    if (!__all(mt <= m_run + 8.f)) {          // T13 defer-max
      float nm = fmaxf(m_run, mt);
      float fr = exp2f(m_run - nm);
      m_run = nm;
      l_run *= fr;
      #pragma unroll
      for (int r = 0; r < 16; ++r) { acc0[r] *= fr; acc1[r] *= fr; }
    }
    unsigned int w[8];
    float ps = 0.f;
    #pragma unroll
    for (int i = 0; i < 8; ++i) {
      float p0 = exp2f(s[2*i]   - m_run);
      float p1 = exp2f(s[2*i+1] - m_run);
      ps += p0 + p1;
      asm("v_cvt_pk_bf16_f32 %0, %1, %2" : "=v"(w[i]) : "v"(p0), "v"(p1));
    }
    ps += __shfl_xor(ps, 32);
    l_run += ps;

    // T12: permlane32_swap builds both halves of each P fragment word
    unsigned int x0 = w[0], x1 = w[1], y0 = w[2], y1 = w[3];
    asm("v_permlane32_swap_b32 %0, %1" : "+v"(x0), "+v"(y0));
    asm("v_permlane32_swap_b32 %0, %1" : "+v"(x1), "+v"(y1));
    unsigned int x2 = w[4], x3 = w[5], y2 = w[6], y3 = w[7];
    asm("v_permlane32_swap_b32 %0, %1" : "+v"(x2), "+v"(y2));
    asm("v_permlane32_swap_b32 %0, %1" : "+v"(x3), "+v"(y3));
    int4v p0i, p1i;
    p0i[0] = (int)x0; p0i[1] = (int)x1; p0i[2] = (int)y0; p0i[3] = (int)y1;
    p1i[0] = (int)x2; p1i[1] = (int)x3; p1i[2] = (int)y2; p1i[3] = (int)y3;
    short8 pa0 = __builtin_bit_cast(short8, p0i);
    short8 pa1 = __builtin_bit_cast(short8, p1i);

    short8 va = *reinterpret_cast<const short8*>(&kvlds[buf][2048 + l*8]);
    short8 vb = *reinterpret_cast<const short8*>(&kvlds[buf][2560 + l*8]);
    short8 vc = *reinterpret_cast<const short8*>(&kvlds[buf][3072 + l*8]);
    short8 vd = *reinterpret_cast<const short8*>(&kvlds[buf][3584 + l*8]);

    __builtin_amdgcn_s_setprio(1);
    acc0 = __builtin_amdgcn_mfma_f32_32x32x16_bf16(va, pa0, acc0, 0, 0, 0);
    acc0 = __builtin_amdgcn_mfma_f32_32x32x16_bf16(vb, pa1, acc0, 0, 0, 0);
    acc1 = __builtin_amdgcn_mfma_f32_32x32x16_bf16(vc, pa0, acc1, 0, 0, 0);
    acc1 = __builtin_amdgcn_mfma_f32_32x32x16_bf16(vd, pa1, acc1, 0, 0, 0);
    __builtin_amdgcn_s_setprio(0);
  };

  stage(0, 0);
  __syncthreads();
  for (int t = 0; ; ) {
    const int cur = t & 1;
    if (t < qt) stage(t + 1, cur ^ 1);   // issue-early: latency hides under compute
    body(t == qt, cur);
    if (++t > qt) break;
    __syncthreads();                     // drains vmcnt (stage done) + lgkm (reads done)
  }

  const float rl = 1.f / l_run;
  unsigned short* op = ctx + (size_t)(b*N_ + qt*32 + lq) * DOUT + h*HD_ + 4*hi;
  #pragma unroll
  for (int dt = 0; dt < 2; ++dt) {
    #pragma unroll
    for (int rq = 0; rq < 4; ++rq) {
      const float a0 = (dt ? acc1[4*rq+0] : acc0[4*rq+0]) * rl;
      const float a1 = (dt ? acc1[4*rq+1] : acc0[4*rq+1]) * rl;
      const float a2 = (dt ? acc1[4*rq+2] : acc0[4*rq+2]) * rl;
      const float a3 = (dt ? acc1[4*rq+3] : acc0[4*rq+3]) * rl;
      ushort4 st;
      st.x = f2bf(a0); st.y = f2bf(a1); st.z = f2bf(a2); st.w = f2bf(a3);
      *reinterpret_cast<ushort4*>(op + dt*32 + rq*8) = st;
    }
  }
}

// ---------------- launcher ----------------
extern "C" void kernel_launch(void* const* d_in, const int* in_sizes, int n_in,
                              void* d_out, int out_size, void* d_ws, size_t ws_size,
                              hipStream_t stream) {
  const float* x    = (const float*)d_in[0];
  const float* cosT = (const float*)d_in[1];
  const float* sinT = (const float*)d_in[2];
  const float* Wq   = (const float*)d_in[4];
  const float* Wk   = (const float*)d_in[5];
  const float* Wv   = (const float*)d_in[6];
  const float* Wo   = (const float*)d_in[7];
  float* out = (float*)d_out;

  char* ws = (char*)d_ws;
  unsigned short* xb     = (unsigned short*)(ws);              // 16.78 MB; reused as ctxb
  unsigned short* ctxb   = xb;
  unsigned short* Wqkv_t = (unsigned short*)(ws + 16777216);   // 12.58 MB (3072 x 2048)
  unsigned short* Wo_t   = (unsigned short*)(ws + 29360128);   //  8.39 MB
  unsigned short* Qp     = (unsigned short*)(ws + 37748736);   // 16.78 MB
  unsigned short* Kp     = (unsigned short*)(ws + 54525952);   //  4.19 MB
  unsigned short* Vp     = (unsigned short*)(ws + 58720256);   //  4.19 MB -> 62,914,560 total

  k_cvt<<<dim3(M_*DIN/4/256), dim3(256), 0, stream>>>(x, xb, M_*DIN/4);

  dim3 tb(32, 8);
  k_transpose<<<dim3(DOUT/32, DIN/32), tb, 0, stream>>>(Wq, Wqkv_t, DIN, DOUT);
  k_transpose<<<dim3(512/32,  DIN/32), tb, 0, stream>>>(Wk, Wqkv_t + (size_t)2048*DIN, DIN, 512);
  k_transpose<<<dim3(512/32,  DIN/32), tb, 0, stream>>>(Wv, Wqkv_t + (size_t)2560*DIN, DIN, 512);
  k_transpose<<<dim3(DOUT/32, DOUT/32), tb, 0, stream>>>(Wo, Wo_t, DOUT, DOUT);

  // fused QKV projection + RoPE + fragment-linear Q/K/V emission (no QKV buffer)
  k_gemm_qkv<<<dim3(3072/128, M_/128), 256, 0, stream>>>(
      xb, Wqkv_t, Qp, Kp, Vp, cosT, sinT);

  k_attn<<<dim3(1024), dim3(256), 0, stream>>>(Qp, Kp, Vp, ctxb);

  k_gemm_out<<<dim3(DOUT/128, M_/128), 256, 0, stream>>>(ctxb, Wo_t, out);
}